// Round 2
// baseline (2465.079 us; speedup 1.0000x reference)
//
#include <hip/hip_runtime.h>
#include <math.h>

// Problem constants
#define T_  256
#define B_  128
#define OBS_ 256
#define H_  512
#define E_  1024
#define DS_ 16
#define DC_ 4
#define DR_ 32
#define M_  (T_*B_)   // 32768 rows for all "flattened (t,b)" GEMMs

typedef unsigned short u16;

__device__ __forceinline__ float sigmoidf_(float v){ return 1.f/(1.f+__expf(-v)); }

__device__ __forceinline__ float b2f(u16 h){
  unsigned int x = ((unsigned int)h) << 16; float f;
  __builtin_memcpy(&f, &x, 4); return f;
}
__device__ __forceinline__ u16 f2b(float f){
  unsigned int x; __builtin_memcpy(&x, &f, 4);
  unsigned int lsb = (x >> 16) & 1u;
  x += 0x7fffu + lsb;            // RNE (values are finite/normal here)
  return (u16)(x >> 16);
}

// ---- typed 4-element load/store helpers (fp32 <-> bf16-as-u16) ----
__device__ __forceinline__ void ld4(const float* p, float v[4]){
  const float4 t = *(const float4*)p; v[0]=t.x; v[1]=t.y; v[2]=t.z; v[3]=t.w;
}
__device__ __forceinline__ void ld4(const u16* p, float v[4]){
  const ushort4 t = *(const ushort4*)p;
  v[0]=b2f(t.x); v[1]=b2f(t.y); v[2]=b2f(t.z); v[3]=b2f(t.w);
}
__device__ __forceinline__ void st4(float* p, const float v[4]){
  *(float4*)p = make_float4(v[0],v[1],v[2],v[3]);
}
__device__ __forceinline__ void st4(u16* p, const float v[4]){
  ushort4 t; t.x=f2b(v[0]); t.y=f2b(v[1]); t.z=f2b(v[2]); t.w=f2b(v[3]);
  *(ushort4*)p = t;
}

// C[m,n] = sum_k A[m*lda+k] * B[n*ldb+k]  (row-major; B used "transposed")
// EP: 0 none, 1 bias+relu, 3 +add residual (fp32), 4 bias only
template<int EP, typename TA, typename TC>
__global__ __launch_bounds__(256) void gemm_nt(
    const TA* __restrict__ A, int lda,
    const float* __restrict__ B, int ldb,
    TC* __restrict__ C, int ldc,
    int K,
    const float* __restrict__ bias,
    const float* __restrict__ add)
{
  __shared__ __align__(16) float As[16][68];
  __shared__ __align__(16) float Bs[16][68];
  const int tid = threadIdx.x;
  const int bm = blockIdx.x * 64, bn = blockIdx.y * 64;
  const int tm = (tid >> 4) << 2;
  const int tn = (tid & 15) << 2;
  const int lr = tid >> 2;          // 0..63 row loaded
  const int lk = (tid & 3) << 2;    // 0,4,8,12 k offset (x4)
  float acc[4][4] = {};
  const TA*    Ap = A + (size_t)(bm + lr) * lda + lk;
  const float* Bp = B + (size_t)(bn + lr) * ldb + lk;
  for (int k0 = 0; k0 < K; k0 += 16) {
    float av[4], bv[4];
    ld4(Ap + k0, av);
    ld4(Bp + k0, bv);
    __syncthreads();
    As[lk+0][lr]=av[0]; As[lk+1][lr]=av[1]; As[lk+2][lr]=av[2]; As[lk+3][lr]=av[3];
    Bs[lk+0][lr]=bv[0]; Bs[lk+1][lr]=bv[1]; Bs[lk+2][lr]=bv[2]; Bs[lk+3][lr]=bv[3];
    __syncthreads();
#pragma unroll
    for (int kk = 0; kk < 16; ++kk) {
      const float4 a4 = *(const float4*)&As[kk][tm];
      const float4 b4 = *(const float4*)&Bs[kk][tn];
      const float a[4] = {a4.x,a4.y,a4.z,a4.w};
      const float b[4] = {b4.x,b4.y,b4.z,b4.w};
#pragma unroll
      for (int i=0;i<4;i++)
#pragma unroll
        for (int j=0;j<4;j++)
          acc[i][j] = fmaf(a[i], b[j], acc[i][j]);
    }
  }
#pragma unroll
  for (int i=0;i<4;i++){
    const size_t row = (size_t)(bm+tm+i);
    float v[4];
#pragma unroll
    for (int j=0;j<4;j++){
      float t = acc[i][j];
      if (EP==1 || EP==4) t += bias[bn+tn+j];
      if (EP==1) t = fmaxf(t, 0.f);
      if (EP==3) t += add[row*(size_t)ldc + bn+tn+j];
      v[j] = t;
    }
    st4(&C[row*(size_t)ldc + bn+tn], v);
  }
}

// xc[t,b,e] = silu( sum_j conv_w[e,j] * masked_src(t-3+j) + conv_b[e] )
__global__ __launch_bounds__(256) void conv_kernel(
    const u16* __restrict__ xz, const float* __restrict__ conv_state,
    const int* __restrict__ dones,
    const float* __restrict__ conv_w, const float* __restrict__ conv_b,
    u16* __restrict__ xc)
{
  const int idx = blockIdx.x * 256 + threadIdx.x;   // over T*B*E
  const int e = idx & (E_-1);
  const int rest = idx >> 10;
  const int b = rest & (B_-1);
  const int t = rest >> 7;
  const float w0 = conv_w[e*4+0], w1 = conv_w[e*4+1], w2 = conv_w[e*4+2], w3 = conv_w[e*4+3];
  const float* cs = conv_state + ((size_t)(b*E_+e))*4;

  float val = w3 * b2f(xz[((size_t)(t*B_+b))*(2*E_) + e]);
  float m = 1.f;
  { const int s = t-1;
    if (s >= 0){ m *= 1.f - (float)dones[s*B_+b]; val += w2 * m * b2f(xz[((size_t)(s*B_+b))*(2*E_) + e]); }
    else       { val += w2 * m * cs[s+4]; } }
  { const int s = t-2;
    if (s >= 0){ m *= 1.f - (float)dones[s*B_+b]; val += w1 * m * b2f(xz[((size_t)(s*B_+b))*(2*E_) + e]); }
    else       { val += w1 * m * cs[s+4]; } }
  { const int s = t-3;
    if (s >= 0){ m *= 1.f - (float)dones[s*B_+b]; val += w0 * m * b2f(xz[((size_t)(s*B_+b))*(2*E_) + e]); }
    else       { val += w0 * m * cs[s+4]; } }

  val += conv_b[e];
  xc[idx] = f2b(val * sigmoidf_(val));   // silu
}

// One thread per (b,e): computes dt on the fly (32-FMA dot vs W_dt row held in
// registers; xdb row pointer is block-uniform -> scalar loads), runs the
// 16-state diagonal recurrence, writes g = y*silu(z) over the z half of xz.
__global__ __launch_bounds__(256) void scan_kernel(
    const u16* __restrict__ xc, const float* __restrict__ xdb,
    u16* __restrict__ xz,
    const int* __restrict__ dones,
    const float* __restrict__ ssm_state, const float* __restrict__ A_log,
    const float* __restrict__ Dvec,
    const float* __restrict__ W_dt, const float* __restrict__ b_dt)
{
  const int e = blockIdx.x * 256 + threadIdx.x;  // grid.x = E_/256
  const int b = blockIdx.y;
  float wdt[DR_], Ae[DS_], s[DS_];
#pragma unroll
  for (int r=0;r<DR_;r+=4){ float v[4]; ld4(W_dt + (size_t)e*DR_ + r, v);
    wdt[r]=v[0]; wdt[r+1]=v[1]; wdt[r+2]=v[2]; wdt[r+3]=v[3]; }
#pragma unroll
  for (int n=0;n<DS_;n++){
    Ae[n] = -expf(A_log[e*DS_+n]);
    s[n]  = ssm_state[((size_t)(b*E_+e))*DS_ + n];
  }
  const float bdt = b_dt[e];
  const float Dv = Dvec[e];
  for (int t=0;t<T_;t++){
    const int rb = t*B_ + b;
    const float* row = xdb + (size_t)rb*64;    // [0:32)=dt_r, [32:48)=B, [48:64)=C (uniform)
    float draw = bdt;
#pragma unroll
    for (int r=0;r<DR_;r++) draw = fmaf(row[r], wdt[r], draw);
    const float dtv = fmaxf(draw,0.f) + log1pf(__expf(-fabsf(draw)));  // softplus
    const float xcv = b2f(xc[(size_t)rb*E_ + e]);
    u16* zp = xz + (size_t)rb*(2*E_) + E_ + e;
    const float zv = b2f(*zp);
    const float xdt = xcv * dtv;
    float y = Dv * xcv;
#pragma unroll
    for (int n=0;n<DS_;n++){
      const float dA = __expf(dtv * Ae[n]);
      s[n] = fmaf(s[n], dA, xdt * row[32+n]);
      y = fmaf(s[n], row[48+n], y);
    }
    const float mask = dones[rb] ? 0.f : 1.f;
#pragma unroll
    for (int n=0;n<DS_;n++) s[n] *= mask;
    *zp = f2b(y * zv * sigmoidf_(zv));          // g = y * silu(z)
  }
}

// In-place LayerNorm over rows of length 512 (fp32).
__global__ __launch_bounds__(256) void ln_kernel(
    float* __restrict__ h, const float* __restrict__ gamma, const float* __restrict__ beta)
{
  const int row = blockIdx.x;
  const int tid = threadIdx.x;
  float* p = h + (size_t)row * H_;
  const float v0 = p[tid], v1 = p[tid+256];
  float sum = v0 + v1, sq = v0*v0 + v1*v1;
#pragma unroll
  for (int o=32;o>0;o>>=1){ sum += __shfl_down(sum,o); sq += __shfl_down(sq,o); }
  __shared__ float ss[4], qq[4], mv[2];
  const int wid = tid >> 6;
  if ((tid & 63) == 0){ ss[wid]=sum; qq[wid]=sq; }
  __syncthreads();
  if (tid == 0){
    const float st = ss[0]+ss[1]+ss[2]+ss[3];
    const float qt = qq[0]+qq[1]+qq[2]+qq[3];
    const float mu = st * (1.f/H_);
    const float var = qt * (1.f/H_) - mu*mu;
    mv[0] = mu; mv[1] = rsqrtf(var + 1e-5f);
  }
  __syncthreads();
  const float mu = mv[0], r = mv[1];
  p[tid]     = (v0-mu)*r*gamma[tid]     + beta[tid];
  p[tid+256] = (v1-mu)*r*gamma[tid+256] + beta[tid+256];
}

extern "C" void kernel_launch(void* const* d_in, const int* in_sizes, int n_in,
                              void* d_out, int out_size, void* d_ws, size_t ws_size,
                              hipStream_t stream)
{
  const float* x          = (const float*)d_in[0];
  const int*   dones      = (const int*)  d_in[1];
  const float* conv_state = (const float*)d_in[2];
  const float* ssm_state  = (const float*)d_in[3];
  const float* W_enc      = (const float*)d_in[4];
  const float* b_enc      = (const float*)d_in[5];
  const float* W_in       = (const float*)d_in[6];
  const float* conv_w     = (const float*)d_in[7];
  const float* conv_b     = (const float*)d_in[8];
  const float* W_xproj    = (const float*)d_in[9];
  const float* W_dt       = (const float*)d_in[10];
  const float* b_dt       = (const float*)d_in[11];
  const float* A_log      = (const float*)d_in[12];
  const float* Dv         = (const float*)d_in[13];
  const float* W_out      = (const float*)d_in[14];
  const float* W1         = (const float*)d_in[15];
  const float* b1         = (const float*)d_in[16];
  const float* W2         = (const float*)d_in[17];
  const float* b2         = (const float*)d_in[18];
  const float* gamma      = (const float*)d_in[19];
  const float* beta       = (const float*)d_in[20];

  // Workspace layout — 200 MB total:
  //   xz  : (T,B,2E) bf16 = 134,217,728 B   (xr | z, z later overwritten by g;
  //                                          whole region later reused as h1 fp32)
  //   xc  : (T,B,E)  bf16 =  67,108,864 B   (later reused as h fp32, same size)
  //   xdb : (T,B,64) fp32 =   8,388,608 B
  char* w = (char*)d_ws;
  u16*   xz  = (u16*)w;
  u16*   xc  = (u16*)(w + 134217728);
  float* xdb = (float*)(w + 134217728 + 67108864);
  float* h   = (float*)xc;    // reuse after scan consumes xc
  float* h1  = (float*)xz;    // reuse after GEMM-7 consumes g
  float* out = (float*)d_out; // feats first, then h2 + LN output

  const dim3 blk(256);

  // 1. feats = relu(x @ W_enc^T + b_enc)            -> d_out (fp32)
  gemm_nt<1,float,float><<<dim3(M_/64, H_/64), blk, 0, stream>>>(x, OBS_, W_enc, OBS_, out, H_, OBS_, b_enc, nullptr);
  // 2. xz = feats @ W_in^T                          -> bf16
  gemm_nt<0,float,u16><<<dim3(M_/64, (2*E_)/64), blk, 0, stream>>>(out, H_, W_in, H_, xz, 2*E_, H_, nullptr, nullptr);
  // 3. masked causal conv + silu                    -> xc (bf16)
  conv_kernel<<<dim3((M_*E_)/256), blk, 0, stream>>>(xz, conv_state, dones, conv_w, conv_b, xc);
  // 4. xdb = xc @ W_xproj^T  (N=64)                 -> fp32
  gemm_nt<0,u16,float><<<dim3(M_/64, 1), blk, 0, stream>>>(xc, E_, W_xproj, E_, xdb, 64, E_, nullptr, nullptr);
  // 5. SSM scan (dt fused) -> g over z half of xz
  scan_kernel<<<dim3(E_/256, B_), blk, 0, stream>>>(xc, xdb, xz, dones, ssm_state, A_log, Dv, W_dt, b_dt);
  // 6. h = g @ W_out^T + feats                      -> h (fp32, xc region)
  gemm_nt<3,u16,float><<<dim3(M_/64, H_/64), blk, 0, stream>>>(xz + E_, 2*E_, W_out, E_, h, H_, E_, nullptr, out);
  // 7. h1 = relu(h @ W1^T + b1)                     -> h1 (fp32, xz region)
  gemm_nt<1,float,float><<<dim3(M_/64, H_/64), blk, 0, stream>>>(h, H_, W1, H_, h1, H_, H_, b1, nullptr);
  // 8. h2 = h1 @ W2^T + b2                          -> d_out
  gemm_nt<4,float,float><<<dim3(M_/64, H_/64), blk, 0, stream>>>(h1, H_, W2, H_, out, H_, H_, b2, nullptr);
  // 9. LayerNorm in-place on d_out
  ln_kernel<<<dim3(M_), blk, 0, stream>>>(out, gamma, beta);
}

// Round 3
// 877.548 us; speedup vs baseline: 2.8091x; 2.8091x over previous
//
#include <hip/hip_runtime.h>
#include <math.h>

// Problem constants
#define T_  256
#define B_  128
#define OBS_ 256
#define H_  512
#define E_  1024
#define DS_ 16
#define DC_ 4
#define DR_ 32
#define M_  (T_*B_)   // 32768 flattened (t,b) rows

typedef unsigned short u16;
typedef short short8 __attribute__((ext_vector_type(8)));   // 8 bf16 (4 VGPRs)
typedef float f32x4  __attribute__((ext_vector_type(4)));

__device__ __forceinline__ float sigmoidf_(float v){ return 1.f/(1.f+__expf(-v)); }

__device__ __forceinline__ float b2f(u16 h){
  unsigned int x = ((unsigned int)h) << 16; float f;
  __builtin_memcpy(&f, &x, 4); return f;
}
__device__ __forceinline__ u16 f2b(float f){
  unsigned int x; __builtin_memcpy(&x, &f, 4);
  unsigned int lsb = (x >> 16) & 1u;
  x += 0x7fffu + lsb;            // RNE
  return (u16)(x >> 16);
}
__device__ __forceinline__ void ld4(const float* p, float v[4]){
  const float4 t = *(const float4*)p; v[0]=t.x; v[1]=t.y; v[2]=t.z; v[3]=t.w;
}
__device__ __forceinline__ void st4(u16* p, const float v[4]){
  ushort4 t; t.x=f2b(v[0]); t.y=f2b(v[1]); t.z=f2b(v[2]); t.w=f2b(v[3]);
  *(ushort4*)p = t;
}
__device__ __forceinline__ void store1(float* p, float v){ *p = v; }
__device__ __forceinline__ void store1(u16* p,  float v){ *p = f2b(v); }

// async global->LDS, 16B per lane. LDS dest = wave-uniform base + lane*16.
__device__ __forceinline__ void gl_lds16(const u16* g, u16* l){
  __builtin_amdgcn_global_load_lds(
      (const __attribute__((address_space(1))) void*)g,
      (__attribute__((address_space(3))) void*)l, 16, 0, 0);
}

// fp32 -> bf16 conversion (n % 4 == 0)
__global__ __launch_bounds__(256) void cvt_f2b(const float* __restrict__ in,
                                               u16* __restrict__ out, int n){
  const int i = (blockIdx.x*256 + threadIdx.x)*4;
  if (i < n){ float v[4]; ld4(in+i, v); st4(out+i, v); }
}

// ---------------------------------------------------------------------------
// MFMA bf16 GEMM: C[m,n] = sum_k A[m,k]*B[n,k]; A row-major [M][K] (lda=K),
// B row-major [N][K] (weights). Tile BM x BN, BK=32, 256 thr = 4 waves, each
// wave computes 64x64 via 4x4 mfma_f32_16x16x32_bf16. m97-style staging via
// global_load_lds width=16, 2-barrier K-loop.
// EP: 0 none, 1 bias+relu, 3 +bf16 residual add, 4 bias only
// ---------------------------------------------------------------------------
template<int EP, typename TC, int BM, int BN>
__global__ __launch_bounds__(256) void mgemm(
    const u16* __restrict__ A, int lda,
    const u16* __restrict__ Bm, int ldb,
    TC* __restrict__ C, int ldc, int K,
    const float* __restrict__ bias,
    const u16* __restrict__ add)
{
  constexpr int WC = BN/64;               // wave cols (BM/64 * BN/64 == 4)
  __shared__ __align__(16) u16 sm[(BM+BN)*32];
  u16* sA = sm;
  u16* sB = sm + BM*32;
  const int tid  = threadIdx.x;
  const int bm = blockIdx.x * BM, bn = blockIdx.y * BN;
  const int w = tid >> 6, lane = tid & 63;
  const int wr = (WC==1) ? w : (w >> 1);
  const int wc = (WC==1) ? 0 : (w & 1);
  const int ln = lane & 15, q = lane >> 4;

  const u16* Ag = A  + (size_t)(bm + (tid>>2))*lda + ((tid&3)<<3);
  const u16* Bg = Bm + (size_t)(bn + (tid>>2))*ldb + ((tid&3)<<3);
  const int arow = wr*64 + ln;
  const int brow = wc*64 + ln;

  f32x4 acc[4][4] = {};
  for (int k0 = 0; k0 < K; k0 += 32){
#pragma unroll
    for (int c = 0; c < BM/64; ++c)
      gl_lds16(Ag + (size_t)(c*64)*lda + k0, sA + c*2048 + tid*8);
#pragma unroll
    for (int c = 0; c < BN/64; ++c)
      gl_lds16(Bg + (size_t)(c*64)*ldb + k0, sB + c*2048 + tid*8);
    __syncthreads();                       // vmcnt(0)+barrier: tiles resident
    short8 af[4], bf[4];
#pragma unroll
    for (int i=0;i<4;i++) af[i] = *(const short8*)&sA[(arow + i*16)*32 + q*8];
#pragma unroll
    for (int j=0;j<4;j++) bf[j] = *(const short8*)&sB[(brow + j*16)*32 + q*8];
#pragma unroll
    for (int i=0;i<4;i++)
#pragma unroll
      for (int j=0;j<4;j++)
        acc[i][j] = __builtin_amdgcn_mfma_f32_16x16x32_bf16(af[i], bf[j], acc[i][j], 0,0,0);
    __syncthreads();                       // protect LDS overwrite
  }
  // epilogue: D row = (lane>>4)*4+reg, col = lane&15 (m89/m91-verified)
#pragma unroll
  for (int i=0;i<4;i++){
#pragma unroll
    for (int r=0;r<4;r++){
      const size_t row = (size_t)(bm + wr*64 + i*16 + q*4 + r);
#pragma unroll
      for (int j=0;j<4;j++){
        const int col = bn + wc*64 + j*16 + ln;
        float t = acc[i][j][r];
        if (EP==1 || EP==4) t += bias[col];
        if (EP==1) t = fmaxf(t, 0.f);
        if (EP==3) t += b2f(add[row*(size_t)ldc + col]);
        store1(&C[row*(size_t)ldc + col], t);
      }
    }
  }
}

// xc[t,b,e] = silu( sum_j conv_w[e,j] * masked_src(t-3+j) + conv_b[e] )
__global__ __launch_bounds__(256) void conv_kernel(
    const u16* __restrict__ xr, const float* __restrict__ conv_state,
    const int* __restrict__ dones,
    const float* __restrict__ conv_w, const float* __restrict__ conv_b,
    u16* __restrict__ xc)
{
  const int idx = blockIdx.x * 256 + threadIdx.x;   // over T*B*E
  const int e = idx & (E_-1);
  const int rest = idx >> 10;
  const int b = rest & (B_-1);
  const int t = rest >> 7;
  const float w0 = conv_w[e*4+0], w1 = conv_w[e*4+1], w2 = conv_w[e*4+2], w3 = conv_w[e*4+3];
  const float* cs = conv_state + ((size_t)(b*E_+e))*4;

  float val = w3 * b2f(xr[((size_t)(t*B_+b))*E_ + e]);
  float m = 1.f;
  { const int s = t-1;
    if (s >= 0){ m *= 1.f - (float)dones[s*B_+b]; val += w2 * m * b2f(xr[((size_t)(s*B_+b))*E_ + e]); }
    else       { val += w2 * m * cs[s+4]; } }
  { const int s = t-2;
    if (s >= 0){ m *= 1.f - (float)dones[s*B_+b]; val += w1 * m * b2f(xr[((size_t)(s*B_+b))*E_ + e]); }
    else       { val += w1 * m * cs[s+4]; } }
  { const int s = t-3;
    if (s >= 0){ m *= 1.f - (float)dones[s*B_+b]; val += w0 * m * b2f(xr[((size_t)(s*B_+b))*E_ + e]); }
    else       { val += w0 * m * cs[s+4]; } }

  val += conv_b[e];
  xc[idx] = f2b(val * sigmoidf_(val));   // silu
}

// One thread per (b,e): dt computed on the fly (32-FMA dot, W_dt row in VGPRs,
// xdb row block-uniform -> scalar loads), 16-state diagonal recurrence,
// g = y*silu(z) written over z.
__global__ __launch_bounds__(256) void scan_kernel(
    const u16* __restrict__ xc, const float* __restrict__ xdb,
    u16* __restrict__ zg,
    const int* __restrict__ dones,
    const float* __restrict__ ssm_state, const float* __restrict__ A_log,
    const float* __restrict__ Dvec,
    const float* __restrict__ W_dt, const float* __restrict__ b_dt)
{
  const int e = blockIdx.x * 256 + threadIdx.x;  // grid.x = E_/256
  const int b = blockIdx.y;
  float wdt[DR_], Ae[DS_], s[DS_];
#pragma unroll
  for (int r=0;r<DR_;r+=4){ float v[4]; ld4(W_dt + (size_t)e*DR_ + r, v);
    wdt[r]=v[0]; wdt[r+1]=v[1]; wdt[r+2]=v[2]; wdt[r+3]=v[3]; }
#pragma unroll
  for (int n=0;n<DS_;n++){
    Ae[n] = -expf(A_log[e*DS_+n]);
    s[n]  = ssm_state[((size_t)(b*E_+e))*DS_ + n];
  }
  const float bdt = b_dt[e];
  const float Dv = Dvec[e];
  for (int t=0;t<T_;t++){
    const int rb = t*B_ + b;
    const float* row = xdb + (size_t)rb*64;    // [0:32)=dt_r, [32:48)=B, [48:64)=C
    float draw = bdt;
#pragma unroll
    for (int r=0;r<DR_;r++) draw = fmaf(row[r], wdt[r], draw);
    const float dtv = fmaxf(draw,0.f) + log1pf(__expf(-fabsf(draw)));  // softplus
    const float xcv = b2f(xc[(size_t)rb*E_ + e]);
    u16* zp = zg + (size_t)rb*E_ + e;
    const float zv = b2f(*zp);
    const float xdt = xcv * dtv;
    float y = Dv * xcv;
#pragma unroll
    for (int n=0;n<DS_;n++){
      const float dA = __expf(dtv * Ae[n]);
      s[n] = fmaf(s[n], dA, xdt * row[32+n]);
      y = fmaf(s[n], row[48+n], y);
    }
    const float mask = dones[rb] ? 0.f : 1.f;
#pragma unroll
    for (int n=0;n<DS_;n++) s[n] *= mask;
    *zp = f2b(y * zv * sigmoidf_(zv));          // g = y * silu(z)
  }
}

// In-place LayerNorm over rows of length 512 (fp32).
__global__ __launch_bounds__(256) void ln_kernel(
    float* __restrict__ h, const float* __restrict__ gamma, const float* __restrict__ beta)
{
  const int row = blockIdx.x;
  const int tid = threadIdx.x;
  float* p = h + (size_t)row * H_;
  const float v0 = p[tid], v1 = p[tid+256];
  float sum = v0 + v1, sq = v0*v0 + v1*v1;
#pragma unroll
  for (int o=32;o>0;o>>=1){ sum += __shfl_down(sum,o); sq += __shfl_down(sq,o); }
  __shared__ float ss[4], qq[4], mv[2];
  const int wid = tid >> 6;
  if ((tid & 63) == 0){ ss[wid]=sum; qq[wid]=sq; }
  __syncthreads();
  if (tid == 0){
    const float st = ss[0]+ss[1]+ss[2]+ss[3];
    const float qt = qq[0]+qq[1]+qq[2]+qq[3];
    const float mu = st * (1.f/H_);
    const float var = qt * (1.f/H_) - mu*mu;
    mv[0] = mu; mv[1] = rsqrtf(var + 1e-5f);
  }
  __syncthreads();
  const float mu = mv[0], r = mv[1];
  p[tid]     = (v0-mu)*r*gamma[tid]     + beta[tid];
  p[tid+256] = (v1-mu)*r*gamma[tid+256] + beta[tid+256];
}

extern "C" void kernel_launch(void* const* d_in, const int* in_sizes, int n_in,
                              void* d_out, int out_size, void* d_ws, size_t ws_size,
                              hipStream_t stream)
{
  const float* x          = (const float*)d_in[0];
  const int*   dones      = (const int*)  d_in[1];
  const float* conv_state = (const float*)d_in[2];
  const float* ssm_state  = (const float*)d_in[3];
  const float* W_enc      = (const float*)d_in[4];
  const float* b_enc      = (const float*)d_in[5];
  const float* W_in       = (const float*)d_in[6];
  const float* conv_w     = (const float*)d_in[7];
  const float* conv_b     = (const float*)d_in[8];
  const float* W_xproj    = (const float*)d_in[9];
  const float* W_dt       = (const float*)d_in[10];
  const float* b_dt       = (const float*)d_in[11];
  const float* A_log      = (const float*)d_in[12];
  const float* Dv         = (const float*)d_in[13];
  const float* W_out      = (const float*)d_in[14];
  const float* W1         = (const float*)d_in[15];
  const float* b1         = (const float*)d_in[16];
  const float* W2         = (const float*)d_in[17];
  const float* b2         = (const float*)d_in[18];
  const float* gamma      = (const float*)d_in[19];
  const float* beta       = (const float*)d_in[20];

  // Workspace: 3 x 64MiB regions + 4.6MB bf16 weights = 205.9 MB
  //  R0: xr (steps 2-3) -> xdb fp32 (4-5) -> h1 bf16 (7-8)
  //  R1: z (2-5) -> g (5-6)
  //  R2: x_bf16 (0-1) -> xc (3-5) -> h bf16 (6-7)
  //  d_out: feats bf16 (1-6, first 33.5MB) -> h2 fp32 + LN (8-9)
  char* w = (char*)d_ws;
  u16*   xr   = (u16*)(w + 0);
  float* xdb  = (float*)(w + 0);
  u16*   h1   = (u16*)(w + 0);
  u16*   zg   = (u16*)(w + 67108864);
  u16*   xb   = (u16*)(w + 134217728);
  u16*   xc   = (u16*)(w + 134217728);
  u16*   h    = (u16*)(w + 134217728);
  u16*   wenc = (u16*)(w + 201326592);
  u16*   win  = wenc + 131072;
  u16*   wxp  = win  + 1048576;
  u16*   wout = wxp  + 65536;
  u16*   w1b  = wout + 524288;
  u16*   w2b  = w1b  + 262144;
  u16*   feats = (u16*)d_out;
  float* out   = (float*)d_out;

  const dim3 blk(256);

  // 0. fp32 -> bf16 conversions (weights + x)
  cvt_f2b<<<dim3(8388608/1024), blk, 0, stream>>>(x, xb, 8388608);
  cvt_f2b<<<dim3(131072/1024),  blk, 0, stream>>>(W_enc, wenc, 131072);
  cvt_f2b<<<dim3(1048576/1024), blk, 0, stream>>>(W_in, win, 1048576);
  cvt_f2b<<<dim3(65536/1024),   blk, 0, stream>>>(W_xproj, wxp, 65536);
  cvt_f2b<<<dim3(524288/1024),  blk, 0, stream>>>(W_out, wout, 524288);
  cvt_f2b<<<dim3(262144/1024),  blk, 0, stream>>>(W1, w1b, 262144);
  cvt_f2b<<<dim3(262144/1024),  blk, 0, stream>>>(W2, w2b, 262144);

  // 1. feats = relu(x @ W_enc^T + b_enc)           -> d_out (bf16)
  mgemm<1,u16,128,128><<<dim3(M_/128, H_/128), blk, 0, stream>>>(xb, OBS_, wenc, OBS_, feats, H_, OBS_, b_enc, nullptr);
  // 2a. xr = feats @ W_in[:E]^T                    -> R0 (bf16)
  mgemm<0,u16,128,128><<<dim3(M_/128, E_/128), blk, 0, stream>>>(feats, H_, win, H_, xr, E_, H_, nullptr, nullptr);
  // 2b. z = feats @ W_in[E:]^T                     -> R1 (bf16)
  mgemm<0,u16,128,128><<<dim3(M_/128, E_/128), blk, 0, stream>>>(feats, H_, win + (size_t)E_*H_, H_, zg, E_, H_, nullptr, nullptr);
  // 3. masked causal conv + silu                   -> xc (bf16, R2)
  conv_kernel<<<dim3((M_*E_)/256), blk, 0, stream>>>(xr, conv_state, dones, conv_w, conv_b, xc);
  // 4. xdb = xc @ W_xproj^T (N=64)                 -> fp32 (R0)
  mgemm<0,float,256,64><<<dim3(M_/256, 1), blk, 0, stream>>>(xc, E_, wxp, E_, xdb, 64, E_, nullptr, nullptr);
  // 5. SSM scan (dt fused) -> g over z (R1)
  scan_kernel<<<dim3(E_/256, B_), blk, 0, stream>>>(xc, xdb, zg, dones, ssm_state, A_log, Dv, W_dt, b_dt);
  // 6. h = g @ W_out^T + feats                     -> bf16 (R2)
  mgemm<3,u16,128,128><<<dim3(M_/128, H_/128), blk, 0, stream>>>(zg, E_, wout, E_, h, H_, E_, nullptr, feats);
  // 7. h1 = relu(h @ W1^T + b1)                    -> bf16 (R0)
  mgemm<1,u16,128,128><<<dim3(M_/128, H_/128), blk, 0, stream>>>(h, H_, w1b, H_, h1, H_, H_, b1, nullptr);
  // 8. h2 = h1 @ W2^T + b2                         -> d_out (fp32)
  mgemm<4,float,128,128><<<dim3(M_/128, H_/128), blk, 0, stream>>>(h1, H_, w2b, H_, out, H_, H_, b2, nullptr);
  // 9. LayerNorm in-place on d_out
  ln_kernel<<<dim3(M_), blk, 0, stream>>>(out, gamma, beta);
}

// Round 4
// 818.511 us; speedup vs baseline: 3.0117x; 1.0721x over previous
//
#include <hip/hip_runtime.h>
#include <math.h>

// Problem constants
#define T_  256
#define B_  128
#define OBS_ 256
#define H_  512
#define E_  1024
#define DS_ 16
#define DC_ 4
#define DR_ 32
#define M_  (T_*B_)   // 32768 flattened (t,b) rows

typedef unsigned short u16;
typedef short short8 __attribute__((ext_vector_type(8)));   // 8 bf16 (4 VGPRs)
typedef float f32x4  __attribute__((ext_vector_type(4)));

__device__ __forceinline__ float sigmoidf_(float v){ return 1.f/(1.f+__expf(-v)); }

__device__ __forceinline__ float b2f(u16 h){
  unsigned int x = ((unsigned int)h) << 16; float f;
  __builtin_memcpy(&f, &x, 4); return f;
}
__device__ __forceinline__ u16 f2b(float f){
  unsigned int x; __builtin_memcpy(&x, &f, 4);
  unsigned int lsb = (x >> 16) & 1u;
  x += 0x7fffu + lsb;            // RNE
  return (u16)(x >> 16);
}
__device__ __forceinline__ void ld4(const float* p, float v[4]){
  const float4 t = *(const float4*)p; v[0]=t.x; v[1]=t.y; v[2]=t.z; v[3]=t.w;
}
__device__ __forceinline__ void st4(u16* p, const float v[4]){
  ushort4 t; t.x=f2b(v[0]); t.y=f2b(v[1]); t.z=f2b(v[2]); t.w=f2b(v[3]);
  *(ushort4*)p = t;
}
__device__ __forceinline__ void store1(float* p, float v){ *p = v; }
__device__ __forceinline__ void store1(u16* p,  float v){ *p = f2b(v); }

// async global->LDS, 16B per lane. LDS dest = wave-uniform base + lane*16.
__device__ __forceinline__ void gl_lds16(const u16* g, u16* l){
  __builtin_amdgcn_global_load_lds(
      (const __attribute__((address_space(1))) void*)g,
      (__attribute__((address_space(3))) void*)l, 16, 0, 0);
}

// fp32 -> bf16 conversion (n % 4 == 0)
__global__ __launch_bounds__(256) void cvt_f2b(const float* __restrict__ in,
                                               u16* __restrict__ out, int n){
  const int i = (blockIdx.x*256 + threadIdx.x)*4;
  if (i < n){ float v[4]; ld4(in+i, v); st4(out+i, v); }
}

// All 6 weight tensors in one launch. Sizes in 1024-element chunks:
// enc 128 | in 1024 | xp 64 | out 512 | w1 256 | w2 256  => 2240 blocks
__global__ __launch_bounds__(256) void cvt_weights(
    const float* __restrict__ w_enc, const float* __restrict__ w_in,
    const float* __restrict__ w_xp,  const float* __restrict__ w_out,
    const float* __restrict__ w1,    const float* __restrict__ w2,
    u16* o_enc, u16* o_in, u16* o_xp, u16* o_out, u16* o1, u16* o2)
{
  const int blk = blockIdx.x;
  const float* src; u16* dst; int base;
  if      (blk < 128)  { src=w_enc; dst=o_enc; base=blk; }
  else if (blk < 1152) { src=w_in;  dst=o_in;  base=blk-128; }
  else if (blk < 1216) { src=w_xp;  dst=o_xp;  base=blk-1152; }
  else if (blk < 1728) { src=w_out; dst=o_out; base=blk-1216; }
  else if (blk < 1984) { src=w1;    dst=o1;    base=blk-1728; }
  else                 { src=w2;    dst=o2;    base=blk-1984; }
  const int i = base*1024 + threadIdx.x*4;
  float v[4]; ld4(src+i, v); st4(dst+i, v);
}

// ---------------------------------------------------------------------------
// MFMA bf16 GEMM (m97 structure): C = A @ B^T, BK=32, 256 thr = 4 waves,
// each wave 64x64 via 4x4 mfma_f32_16x16x32_bf16, global_load_lds staging.
// EP: 0 none, 1 bias+relu, 3 +bf16 residual, 4 bias only
// ---------------------------------------------------------------------------
template<int EP, typename TC, int BM, int BN>
__global__ __launch_bounds__(256) void mgemm(
    const u16* __restrict__ A, int lda,
    const u16* __restrict__ Bm, int ldb,
    TC* __restrict__ C, int ldc, int K,
    const float* __restrict__ bias,
    const u16* __restrict__ add)
{
  constexpr int WC = BN/64;               // wave cols (BM/64 * BN/64 == 4)
  __shared__ __align__(16) u16 sm[(BM+BN)*32];
  u16* sA = sm;
  u16* sB = sm + BM*32;
  const int tid  = threadIdx.x;
  const int bm = blockIdx.x * BM, bn = blockIdx.y * BN;
  const int w = tid >> 6, lane = tid & 63;
  const int wr = (WC==1) ? w : (w >> 1);
  const int wc = (WC==1) ? 0 : (w & 1);
  const int ln = lane & 15, q = lane >> 4;

  const u16* Ag = A  + (size_t)(bm + (tid>>2))*lda + ((tid&3)<<3);
  const u16* Bg = Bm + (size_t)(bn + (tid>>2))*ldb + ((tid&3)<<3);
  const int arow = wr*64 + ln;
  const int brow = wc*64 + ln;

  f32x4 acc[4][4] = {};
  for (int k0 = 0; k0 < K; k0 += 32){
#pragma unroll
    for (int c = 0; c < BM/64; ++c)
      gl_lds16(Ag + (size_t)(c*64)*lda + k0, sA + c*2048 + tid*8);
#pragma unroll
    for (int c = 0; c < BN/64; ++c)
      gl_lds16(Bg + (size_t)(c*64)*ldb + k0, sB + c*2048 + tid*8);
    __syncthreads();
    short8 af[4], bf[4];
#pragma unroll
    for (int i=0;i<4;i++) af[i] = *(const short8*)&sA[(arow + i*16)*32 + q*8];
#pragma unroll
    for (int j=0;j<4;j++) bf[j] = *(const short8*)&sB[(brow + j*16)*32 + q*8];
#pragma unroll
    for (int i=0;i<4;i++)
#pragma unroll
      for (int j=0;j<4;j++)
        acc[i][j] = __builtin_amdgcn_mfma_f32_16x16x32_bf16(af[i], bf[j], acc[i][j], 0,0,0);
    __syncthreads();
  }
#pragma unroll
  for (int i=0;i<4;i++){
#pragma unroll
    for (int r=0;r<4;r++){
      const size_t row = (size_t)(bm + wr*64 + i*16 + q*4 + r);
#pragma unroll
      for (int j=0;j<4;j++){
        const int col = bn + wc*64 + j*16 + ln;
        float t = acc[i][j][r];
        if (EP==1 || EP==4) t += bias[col];
        if (EP==1) t = fmaxf(t, 0.f);
        if (EP==3) t += b2f(add[row*(size_t)ldc + col]);
        store1(&C[row*(size_t)ldc + col], t);
      }
    }
  }
}

// xc[t,b,e] = silu( sum_j conv_w[e,j] * masked_src(t-3+j) + conv_b[e] )
__global__ __launch_bounds__(256) void conv_kernel(
    const u16* __restrict__ xr, const float* __restrict__ conv_state,
    const int* __restrict__ dones,
    const float* __restrict__ conv_w, const float* __restrict__ conv_b,
    u16* __restrict__ xc)
{
  const int idx = blockIdx.x * 256 + threadIdx.x;   // over T*B*E
  const int e = idx & (E_-1);
  const int rest = idx >> 10;
  const int b = rest & (B_-1);
  const int t = rest >> 7;
  const float w0 = conv_w[e*4+0], w1 = conv_w[e*4+1], w2 = conv_w[e*4+2], w3 = conv_w[e*4+3];
  const float* cs = conv_state + ((size_t)(b*E_+e))*4;

  float val = w3 * b2f(xr[((size_t)(t*B_+b))*E_ + e]);
  float m = 1.f;
  { const int s = t-1;
    if (s >= 0){ m *= 1.f - (float)dones[s*B_+b]; val += w2 * m * b2f(xr[((size_t)(s*B_+b))*E_ + e]); }
    else       { val += w2 * m * cs[s+4]; } }
  { const int s = t-2;
    if (s >= 0){ m *= 1.f - (float)dones[s*B_+b]; val += w1 * m * b2f(xr[((size_t)(s*B_+b))*E_ + e]); }
    else       { val += w1 * m * cs[s+4]; } }
  { const int s = t-3;
    if (s >= 0){ m *= 1.f - (float)dones[s*B_+b]; val += w0 * m * b2f(xr[((size_t)(s*B_+b))*E_ + e]); }
    else       { val += w0 * m * cs[s+4]; } }

  val += conv_b[e];
  xc[idx] = f2b(val * sigmoidf_(val));   // silu
}

// One thread per (b,e). Row of xdb loaded as 16 float4 (block-uniform addr),
// dt-dot with 4 parallel accumulators, 16-state diagonal recurrence,
// g = y*silu(z) over z.  2 waves/SIMD resident -> allow full VGPR budget.
__global__ __launch_bounds__(256, 2) void scan_kernel(
    const u16* __restrict__ xc, const float* __restrict__ xdb,
    u16* __restrict__ zg,
    const int* __restrict__ dones,
    const float* __restrict__ ssm_state, const float* __restrict__ A_log,
    const float* __restrict__ Dvec,
    const float* __restrict__ W_dt, const float* __restrict__ b_dt)
{
  const int e = blockIdx.x * 256 + threadIdx.x;  // grid.x = E_/256
  const int b = blockIdx.y;
  float wdt[DR_], Ae[DS_], s[DS_];
#pragma unroll
  for (int r=0;r<DR_;r+=4){ float v[4]; ld4(W_dt + (size_t)e*DR_ + r, v);
    wdt[r]=v[0]; wdt[r+1]=v[1]; wdt[r+2]=v[2]; wdt[r+3]=v[3]; }
#pragma unroll
  for (int n=0;n<DS_;n++){
    Ae[n] = -expf(A_log[e*DS_+n]);
    s[n]  = ssm_state[((size_t)(b*E_+e))*DS_ + n];
  }
  const float bdt = b_dt[e];
  const float Dv = Dvec[e];

  const float4* rp  = (const float4*)xdb + (size_t)b*16;  // row (t=0,b), 16 float4
  const u16*    xcp = xc + (size_t)b*E_ + e;
  u16*          zp  = zg + (size_t)b*E_ + e;
  const int*    dp  = dones + b;

#pragma unroll 2
  for (int t=0;t<T_;t++){
    float4 r[16];
#pragma unroll
    for (int i=0;i<16;i++) r[i] = rp[i];
    const float xcv = b2f(*xcp);
    const float zv  = b2f(*zp);
    const int   dn  = *dp;

    // dt = softplus( xdb[0:32] . wdt + bdt ), 4 parallel chains
    float a0 = bdt, a1 = 0.f, a2 = 0.f, a3 = 0.f;
#pragma unroll
    for (int i=0;i<8;i++){
      a0 = fmaf(r[i].x, wdt[4*i+0], a0);
      a1 = fmaf(r[i].y, wdt[4*i+1], a1);
      a2 = fmaf(r[i].z, wdt[4*i+2], a2);
      a3 = fmaf(r[i].w, wdt[4*i+3], a3);
    }
    const float draw = (a0+a1)+(a2+a3);
    const float dtv  = fmaxf(draw,0.f) + __logf(1.f + __expf(-fabsf(draw)));

    float Bv[16], Cv[16];
#pragma unroll
    for (int i=0;i<4;i++){
      Bv[4*i+0]=r[8+i].x;  Bv[4*i+1]=r[8+i].y;  Bv[4*i+2]=r[8+i].z;  Bv[4*i+3]=r[8+i].w;
      Cv[4*i+0]=r[12+i].x; Cv[4*i+1]=r[12+i].y; Cv[4*i+2]=r[12+i].z; Cv[4*i+3]=r[12+i].w;
    }
    const float xdt = xcv * dtv;
    float y0 = Dv * xcv, y1 = 0.f;
#pragma unroll
    for (int n=0;n<DS_;n++){
      const float dA = __expf(dtv * Ae[n]);
      s[n] = fmaf(s[n], dA, xdt * Bv[n]);
      if (n & 1) y1 = fmaf(s[n], Cv[n], y1);
      else       y0 = fmaf(s[n], Cv[n], y0);
    }
    const float mask = dn ? 0.f : 1.f;
#pragma unroll
    for (int n=0;n<DS_;n++) s[n] *= mask;
    *zp = f2b((y0+y1) * zv * sigmoidf_(zv));     // g = y * silu(z)

    rp  += (size_t)B_*16;
    xcp += (size_t)B_*E_;
    zp  += (size_t)B_*E_;
    dp  += B_;
  }
}

// In-place LayerNorm over rows of length 512 (fp32).
__global__ __launch_bounds__(256) void ln_kernel(
    float* __restrict__ h, const float* __restrict__ gamma, const float* __restrict__ beta)
{
  const int row = blockIdx.x;
  const int tid = threadIdx.x;
  float* p = h + (size_t)row * H_;
  const float v0 = p[tid], v1 = p[tid+256];
  float sum = v0 + v1, sq = v0*v0 + v1*v1;
#pragma unroll
  for (int o=32;o>0;o>>=1){ sum += __shfl_down(sum,o); sq += __shfl_down(sq,o); }
  __shared__ float ss[4], qq[4], mv[2];
  const int wid = tid >> 6;
  if ((tid & 63) == 0){ ss[wid]=sum; qq[wid]=sq; }
  __syncthreads();
  if (tid == 0){
    const float st = ss[0]+ss[1]+ss[2]+ss[3];
    const float qt = qq[0]+qq[1]+qq[2]+qq[3];
    const float mu = st * (1.f/H_);
    const float var = qt * (1.f/H_) - mu*mu;
    mv[0] = mu; mv[1] = rsqrtf(var + 1e-5f);
  }
  __syncthreads();
  const float mu = mv[0], r = mv[1];
  p[tid]     = (v0-mu)*r*gamma[tid]     + beta[tid];
  p[tid+256] = (v1-mu)*r*gamma[tid+256] + beta[tid+256];
}

extern "C" void kernel_launch(void* const* d_in, const int* in_sizes, int n_in,
                              void* d_out, int out_size, void* d_ws, size_t ws_size,
                              hipStream_t stream)
{
  const float* x          = (const float*)d_in[0];
  const int*   dones      = (const int*)  d_in[1];
  const float* conv_state = (const float*)d_in[2];
  const float* ssm_state  = (const float*)d_in[3];
  const float* W_enc      = (const float*)d_in[4];
  const float* b_enc      = (const float*)d_in[5];
  const float* W_in       = (const float*)d_in[6];
  const float* conv_w     = (const float*)d_in[7];
  const float* conv_b     = (const float*)d_in[8];
  const float* W_xproj    = (const float*)d_in[9];
  const float* W_dt       = (const float*)d_in[10];
  const float* b_dt       = (const float*)d_in[11];
  const float* A_log      = (const float*)d_in[12];
  const float* Dv         = (const float*)d_in[13];
  const float* W_out      = (const float*)d_in[14];
  const float* W1         = (const float*)d_in[15];
  const float* b1         = (const float*)d_in[16];
  const float* W2         = (const float*)d_in[17];
  const float* b2         = (const float*)d_in[18];
  const float* gamma      = (const float*)d_in[19];
  const float* beta       = (const float*)d_in[20];

  // Workspace: 3 x 64MiB regions + 4.6MB bf16 weights = 205.9 MB (known-good)
  //  R0: xr (2-3) -> xdb fp32 (4-5) -> h1 bf16 (7-8)
  //  R1: z (2-5) -> g (5-6)
  //  R2: x_bf16 (0-1) -> xc (3-5) -> h bf16 (6-7)
  //  d_out: feats bf16 (1-6) -> h2 fp32 + LN (8-9)
  char* w = (char*)d_ws;
  u16*   xr   = (u16*)(w + 0);
  float* xdb  = (float*)(w + 0);
  u16*   h1   = (u16*)(w + 0);
  u16*   zg   = (u16*)(w + 67108864);
  u16*   xb   = (u16*)(w + 134217728);
  u16*   xc   = (u16*)(w + 134217728);
  u16*   h    = (u16*)(w + 134217728);
  u16*   wenc = (u16*)(w + 201326592);
  u16*   win  = wenc + 131072;
  u16*   wxp  = win  + 1048576;
  u16*   wout = wxp  + 65536;
  u16*   w1b  = wout + 524288;
  u16*   w2b  = w1b  + 262144;
  u16*   feats = (u16*)d_out;
  float* out   = (float*)d_out;

  const dim3 blk(256);

  // 0. fp32 -> bf16 conversions
  cvt_f2b<<<dim3(8388608/1024), blk, 0, stream>>>(x, xb, 8388608);
  cvt_weights<<<dim3(2240), blk, 0, stream>>>(W_enc, W_in, W_xproj, W_out, W1, W2,
                                              wenc, win, wxp, wout, w1b, w2b);

  // 1. feats = relu(x @ W_enc^T + b_enc)           -> d_out (bf16)
  mgemm<1,u16,128,128><<<dim3(M_/128, H_/128), blk, 0, stream>>>(xb, OBS_, wenc, OBS_, feats, H_, OBS_, b_enc, nullptr);
  // 2a. xr = feats @ W_in[:E]^T                    -> R0 (bf16)
  mgemm<0,u16,128,128><<<dim3(M_/128, E_/128), blk, 0, stream>>>(feats, H_, win, H_, xr, E_, H_, nullptr, nullptr);
  // 2b. z = feats @ W_in[E:]^T                     -> R1 (bf16)
  mgemm<0,u16,128,128><<<dim3(M_/128, E_/128), blk, 0, stream>>>(feats, H_, win + (size_t)E_*H_, H_, zg, E_, H_, nullptr, nullptr);
  // 3. masked causal conv + silu                   -> xc (bf16, R2)
  conv_kernel<<<dim3((M_*E_)/256), blk, 0, stream>>>(xr, conv_state, dones, conv_w, conv_b, xc);
  // 4. xdb = xc @ W_xproj^T (N=64)                 -> fp32 (R0)
  mgemm<0,float,256,64><<<dim3(M_/256, 1), blk, 0, stream>>>(xc, E_, wxp, E_, xdb, 64, E_, nullptr, nullptr);
  // 5. SSM scan (dt fused) -> g over z (R1)
  scan_kernel<<<dim3(E_/256, B_), blk, 0, stream>>>(xc, xdb, zg, dones, ssm_state, A_log, Dv, W_dt, b_dt);
  // 6. h = g @ W_out^T + feats                     -> bf16 (R2)
  mgemm<3,u16,128,128><<<dim3(M_/128, H_/128), blk, 0, stream>>>(zg, E_, wout, E_, h, H_, E_, nullptr, feats);
  // 7. h1 = relu(h @ W1^T + b1)                    -> bf16 (R0)
  mgemm<1,u16,128,128><<<dim3(M_/128, H_/128), blk, 0, stream>>>(h, H_, w1b, H_, h1, H_, H_, b1, nullptr);
  // 8. h2 = h1 @ W2^T + b2                         -> d_out (fp32)
  mgemm<4,float,128,128><<<dim3(M_/128, H_/128), blk, 0, stream>>>(h1, H_, w2b, H_, out, H_, H_, b2, nullptr);
  // 9. LayerNorm in-place on d_out
  ln_kernel<<<dim3(M_), blk, 0, stream>>>(out, gamma, beta);
}